// Round 3
// baseline (222.663 us; speedup 1.0000x reference)
//
#include <hip/hip_runtime.h>

#define NNODES 50000
#define NEDGES 640000
#define DIM 128
#define SCAN_BLK 49   // ceil(50000 / 1024)
#define NSLICE 8      // column slices (16 cols each) -> per-XCD L2-resident table
#define SLICE_U16 800000   // 50000 nodes * 16 u16 per slice

typedef unsigned short u16;
typedef __attribute__((ext_vector_type(8))) short short8;   // 8 bf16 (4 VGPRs)
typedef __attribute__((ext_vector_type(4))) float f32x4;

// ---------------- bf16 helpers ----------------
__device__ __forceinline__ unsigned int bf16rne(float f) {
    unsigned int u = __float_as_uint(f);
    return (u + 0x7FFFu + ((u >> 16) & 1u)) >> 16;   // RNE (no NaN inputs)
}
__device__ __forceinline__ float bflo(unsigned int p) { return __uint_as_float(p << 16); }
__device__ __forceinline__ float bfhi(unsigned int p) { return __uint_as_float(p & 0xFFFF0000u); }

// ---------------- fused prep: cvt x -> slice-major bf16 | cvt W1,W2 -> bf16^T | deg = 0 ----
// xb layout: xb[s][node][16] u16  (s = col/16). Slice s is a contiguous 1.6 MB block.
#define CVT_BLKS   3125   // 50000 rows / 16 rows per block
#define CVTW_BLKS  128    // 32768 / 256
#define DEG_BLKS   196    // ceil(50000 / 256)
__global__ void prep_k(const float4* __restrict__ x4, u16* __restrict__ xb,
                       const float* __restrict__ W1, const float* __restrict__ W2,
                       u16* __restrict__ wt, int* __restrict__ deg) {
    const int b = blockIdx.x, t = threadIdx.x;
    if (b < CVT_BLKS) {
        int n = b * 16 + (t >> 4);        // row
        int c = t & 15;                   // 8-col chunk within row (coalesced input read)
        float4 a = x4[n * 32 + c * 2];
        float4 d = x4[n * 32 + c * 2 + 1];
        uint4 o;
        o.x = bf16rne(a.x) | (bf16rne(a.y) << 16);
        o.y = bf16rne(a.z) | (bf16rne(a.w) << 16);
        o.z = bf16rne(d.x) | (bf16rne(d.y) << 16);
        o.w = bf16rne(d.z) | (bf16rne(d.w) << 16);
        int s = c >> 1, h = c & 1;
        *(uint4*)(xb + (size_t)s * SLICE_U16 + (size_t)n * 16 + h * 8) = o;
    } else if (b < CVT_BLKS + CVTW_BLKS) {
        int i = (b - CVT_BLKS) * 256 + t;          // < 32768
        const float* W = (i < DIM * DIM) ? W1 : W2;
        int li = i & (DIM * DIM - 1);
        int n = li >> 7, k = li & 127;
        wt[i] = (u16)bf16rne(W[k * DIM + n]);
    } else {
        int i = (b - CVT_BLKS - CVTW_BLKS) * 256 + t;
        if (i < NNODES) deg[i] = 0;
    }
}

// ---------------- CSR build: hist -> scan -> fill (u16 srclist) ----------------
__global__ void hist_k(const int* __restrict__ ei, int* __restrict__ deg, int E) {
    int e = blockIdx.x * blockDim.x + threadIdx.x;
    if (e < E) atomicAdd(&deg[ei[E + e]], 1);
}

__global__ void scanA_k(const int* __restrict__ deg, int* __restrict__ bsum) {
    const int t = threadIdx.x, b = blockIdx.x;
    const int base = b * 1024 + t * 4;
    int4 v = make_int4(0, 0, 0, 0);
    if (base < NNODES) v = *(const int4*)&deg[base];
    int s = v.x + v.y + v.z + v.w;
    #pragma unroll
    for (int d = 32; d > 0; d >>= 1) s += __shfl_down(s, d, 64);
    __shared__ int ws[4];
    if ((t & 63) == 0) ws[t >> 6] = s;
    __syncthreads();
    if (t == 0) bsum[b] = ws[0] + ws[1] + ws[2] + ws[3];
}

__global__ void scanC_k(const int* __restrict__ deg, const int* __restrict__ bsum,
                        int* __restrict__ off, int* __restrict__ cur) {
    __shared__ int ws[4];
    __shared__ int sbase;
    const int t = threadIdx.x, b = blockIdx.x;
    if (t < 64) {
        int v = (t < SCAN_BLK && t < b) ? bsum[t] : 0;
        #pragma unroll
        for (int d = 32; d > 0; d >>= 1) v += __shfl_down(v, d, 64);
        if (t == 0) sbase = v;
    }
    const int base = b * 1024 + t * 4;
    int4 v = make_int4(0, 0, 0, 0);
    if (base < NNODES) v = *(const int4*)&deg[base];
    const int s = v.x + v.y + v.z + v.w;
    const int lane = t & 63, w = t >> 6;
    int sv = s;
    #pragma unroll
    for (int d = 1; d < 64; d <<= 1) {
        int u = __shfl_up(sv, d, 64);
        if (lane >= d) sv += u;
    }
    if (lane == 63) ws[w] = sv;
    __syncthreads();
    int wbase = 0;
    #pragma unroll
    for (int i = 0; i < 4; ++i) if (i < w) wbase += ws[i];
    int ex = sbase + wbase + (sv - s);
    if (base < NNODES) {
        int4 o;
        o.x = ex;
        o.y = o.x + v.x;
        o.z = o.y + v.y;
        o.w = o.z + v.z;
        *(int4*)&off[base] = o;
        *(int4*)&cur[base] = o;
    }
    if (b == 0 && t == 0) off[NNODES] = NEDGES;
}

__global__ void fill16_k(const int* __restrict__ ei, int* __restrict__ cur,
                         u16* __restrict__ sl, int E) {
    int e = blockIdx.x * blockDim.x + threadIdx.x;
    if (e >= E) return;
    int src = ei[e];
    int dst = ei[E + e];
    int pos = atomicAdd(&cur[dst], 1);
    sl[pos] = (u16)src;
}

// ---------------- col-sliced, XCD-affine gather ----------------
// Block b handles slice (b & 7) for 128 nodes; consecutive blocks -> different XCDs,
// so XCD k streams only slice k (1.6 MB, L2-resident). srclist u16 read is sequential.
// Output hpb holds ONLY the aggregate (self term added in MLP via a second MFMA).
__launch_bounds__(256)
__global__ void gather_cs_k(const u16* __restrict__ xb, const int* __restrict__ off,
                            const u16* __restrict__ sl, u16* __restrict__ hpb) {
    const int b = blockIdx.x;
    const int s = b & 7, chunk = b >> 3;
    const int t = threadIdx.x;
    const int n = chunk * 128 + (t >> 1);
    if (n >= NNODES) return;
    const int h = t & 1;
    const u16* __restrict__ slice = xb + (size_t)s * SLICE_U16;
    int j = off[n];
    const int end = off[n + 1];
    float a0 = 0.f, a1 = 0.f, a2 = 0.f, a3 = 0.f, a4 = 0.f, a5 = 0.f, a6 = 0.f, a7 = 0.f;
    for (; j < end; ++j) {
        int src = sl[j];
        uint4 q = *(const uint4*)(slice + (size_t)src * 16 + h * 8);
        a0 += bflo(q.x); a1 += bfhi(q.x);
        a2 += bflo(q.y); a3 += bfhi(q.y);
        a4 += bflo(q.z); a5 += bfhi(q.z);
        a6 += bflo(q.w); a7 += bfhi(q.w);
    }
    uint4 o;
    o.x = bf16rne(a0) | (bf16rne(a1) << 16);
    o.y = bf16rne(a2) | (bf16rne(a3) << 16);
    o.z = bf16rne(a4) | (bf16rne(a5) << 16);
    o.w = bf16rne(a6) | (bf16rne(a7) << 16);
    *(uint4*)(hpb + (size_t)s * SLICE_U16 + (size_t)n * 16 + h * 8) = o;
}

// ---------------- MFMA MLP: layer1 A = x + agg via two MFMAs (linearity) ----------------
__launch_bounds__(256)
__global__ void mlp_mfma_k(const u16* __restrict__ xb, const u16* __restrict__ hpb,
                           float* __restrict__ outp,
                           const u16* __restrict__ w1t, const float* __restrict__ b1,
                           const u16* __restrict__ w2t, const float* __restrict__ b2) {
    __shared__ __align__(16) u16 Abuf[4][16][136];   // 17 KB; pitch 136 -> 2-way max (free)

    const int tid = threadIdx.x;
    const int wv = tid >> 6, lane = tid & 63;
    const int quad = lane >> 4, msel = lane & 15;
    const int rowbase = blockIdx.x * 64 + wv * 16;
    int rowA = rowbase + msel;
    if (rowA >= NNODES) rowA = NNODES - 1;           // clamp; stores predicated

    f32x4 acc[8];
    #pragma unroll
    for (int t = 0; t < 8; ++t) acc[t] = (f32x4){0.f, 0.f, 0.f, 0.f};

    // ---- layer 1: (x + agg) W1 = xW1 + aggW1 ----
    #pragma unroll
    for (int it = 0; it < 4; ++it) {
        // cols [it*32 + quad*8, +8) in slice-major layout:
        const size_t abase = (size_t)(it * 2 + (quad >> 1)) * SLICE_U16
                           + (size_t)rowA * 16 + (quad & 1) * 8;
        short8 xfr = *(const short8*)(xb + abase);
        short8 gfr = *(const short8*)(hpb + abase);
        #pragma unroll
        for (int t = 0; t < 8; ++t) {
            short8 bfr = *(const short8*)(w1t + (size_t)(t * 16 + msel) * DIM + it * 32 + quad * 8);
            acc[t] = __builtin_amdgcn_mfma_f32_16x16x32_bf16(xfr, bfr, acc[t], 0, 0, 0);
            acc[t] = __builtin_amdgcn_mfma_f32_16x16x32_bf16(gfr, bfr, acc[t], 0, 0, 0);
        }
    }

    // epilogue 1: +b1, relu, bf16 -> Abuf (A-layout for layer 2)
    #pragma unroll
    for (int t = 0; t < 8; ++t) {
        float bb = b1[t * 16 + msel];
        #pragma unroll
        for (int r = 0; r < 4; ++r) {
            float v = fmaxf(acc[t][r] + bb, 0.f);
            Abuf[wv][quad * 4 + r][t * 16 + msel] = (u16)bf16rne(v);
        }
    }
    __syncthreads();

    // ---- layer 2 ----
    #pragma unroll
    for (int t = 0; t < 8; ++t) acc[t] = (f32x4){0.f, 0.f, 0.f, 0.f};
    #pragma unroll
    for (int it = 0; it < 4; ++it) {
        short8 afr = *(const short8*)&Abuf[wv][msel][it * 32 + quad * 8];
        #pragma unroll
        for (int t = 0; t < 8; ++t) {
            short8 bfr = *(const short8*)(w2t + (size_t)(t * 16 + msel) * DIM + it * 32 + quad * 8);
            acc[t] = __builtin_amdgcn_mfma_f32_16x16x32_bf16(afr, bfr, acc[t], 0, 0, 0);
        }
    }

    // epilogue 2: +b2, store f32
    #pragma unroll
    for (int t = 0; t < 8; ++t) {
        float bb = b2[t * 16 + msel];
        #pragma unroll
        for (int r = 0; r < 4; ++r) {
            int row = rowbase + quad * 4 + r;
            if (row < NNODES)
                outp[(size_t)row * DIM + t * 16 + msel] = acc[t][r] + bb;
        }
    }
}

// ================= fallback paths (smaller ws) =================

__global__ void fill_k(const int* __restrict__ ei, int* __restrict__ cur,
                       int* __restrict__ srclist, int E) {
    int e = blockIdx.x * blockDim.x + threadIdx.x;
    if (e >= E) return;
    int src = ei[e];
    int dst = ei[E + e];
    int pos = atomicAdd(&cur[dst], 1);
    srclist[pos] = src;
}

__global__ void zero_k(int* __restrict__ p, int n) {
    int i = blockIdx.x * blockDim.x + threadIdx.x;
    if (i < n) p[i] = 0;
}

__global__ void gather_k(const float4* __restrict__ x4, const int* __restrict__ off,
                         const int* __restrict__ srclist, float4* __restrict__ hp4) {
    int t = blockIdx.x * blockDim.x + threadIdx.x;
    int node = t >> 5;
    if (node >= NNODES) return;
    int lane = t & 31;
    float4 acc = x4[(size_t)node * 32 + lane];
    int beg = off[node], end = off[node + 1];
    for (int j = beg; j < end; ++j) {
        int s = srclist[j];
        float4 v = x4[(size_t)s * 32 + lane];
        acc.x += v.x; acc.y += v.y; acc.z += v.z; acc.w += v.w;
    }
    hp4[(size_t)node * 32 + lane] = acc;
}

__global__ void copy_k(const float4* __restrict__ src, float4* __restrict__ dst, int n4) {
    int i = blockIdx.x * blockDim.x + threadIdx.x;
    if (i < n4) dst[i] = src[i];
}

__global__ void scatter_k(const float4* __restrict__ x4, const int* __restrict__ ei,
                          float* __restrict__ hp, int E) {
    int t = blockIdx.x * blockDim.x + threadIdx.x;
    int e = t >> 5;
    if (e >= E) return;
    int lane = t & 31;
    int src = ei[e];
    int dst = ei[E + e];
    float4 v = x4[(size_t)src * 32 + lane];
    float* p = hp + (size_t)dst * DIM + lane * 4;
    unsafeAtomicAdd(p + 0, v.x);
    unsafeAtomicAdd(p + 1, v.y);
    unsafeAtomicAdd(p + 2, v.z);
    unsafeAtomicAdd(p + 3, v.w);
}

__launch_bounds__(256)
__global__ void mlp_k(float* __restrict__ io,
                      const float* __restrict__ W1, const float* __restrict__ b1,
                      const float* __restrict__ W2, const float* __restrict__ b2,
                      int N) {
    __shared__ float Wl[DIM * DIM];
    __shared__ float As[32][DIM];
    const int tid = threadIdx.x;
    const int r0 = blockIdx.x * 32;
    const int tc = tid & 31;
    const int tr = tid >> 5;
    {
        const float4* w4 = (const float4*)W1;
        float4* wl4 = (float4*)Wl;
        #pragma unroll
        for (int i = 0; i < 16; ++i) wl4[tid + i * 256] = w4[tid + i * 256];
    }
    {
        const float4* io4 = (const float4*)io;
        float4* as4 = (float4*)As;
        #pragma unroll
        for (int i = 0; i < 4; ++i) {
            int p = tid + i * 256;
            int row = p >> 5;
            float4 v = make_float4(0.f, 0.f, 0.f, 0.f);
            if (r0 + row < N) v = io4[(size_t)(r0 + row) * 32 + (p & 31)];
            as4[p] = v;
        }
    }
    __syncthreads();
    float acc[4][4];
    #pragma unroll
    for (int i = 0; i < 4; ++i)
        #pragma unroll
        for (int j = 0; j < 4; ++j) acc[i][j] = 0.f;
    for (int kc = 0; kc < 32; ++kc) {
        float4 a[4], w[4];
        #pragma unroll
        for (int i = 0; i < 4; ++i) a[i] = *(const float4*)&As[tr * 4 + i][kc * 4];
        #pragma unroll
        for (int kk = 0; kk < 4; ++kk) w[kk] = *(const float4*)&Wl[(kc * 4 + kk) * DIM + tc * 4];
        float af[4][4];
        #pragma unroll
        for (int i = 0; i < 4; ++i) {
            af[i][0] = a[i].x; af[i][1] = a[i].y; af[i][2] = a[i].z; af[i][3] = a[i].w;
        }
        #pragma unroll
        for (int kk = 0; kk < 4; ++kk) {
            float wv[4] = {w[kk].x, w[kk].y, w[kk].z, w[kk].w};
            #pragma unroll
            for (int i = 0; i < 4; ++i)
                #pragma unroll
                for (int j = 0; j < 4; ++j)
                    acc[i][j] = fmaf(af[i][kk], wv[j], acc[i][j]);
        }
    }
    float4 bv1 = ((const float4*)b1)[tc];
    float h[4][4];
    #pragma unroll
    for (int i = 0; i < 4; ++i) {
        h[i][0] = fmaxf(acc[i][0] + bv1.x, 0.f);
        h[i][1] = fmaxf(acc[i][1] + bv1.y, 0.f);
        h[i][2] = fmaxf(acc[i][2] + bv1.z, 0.f);
        h[i][3] = fmaxf(acc[i][3] + bv1.w, 0.f);
    }
    __syncthreads();
    {
        const float4* w4 = (const float4*)W2;
        float4* wl4 = (float4*)Wl;
        #pragma unroll
        for (int i = 0; i < 16; ++i) wl4[tid + i * 256] = w4[tid + i * 256];
    }
    #pragma unroll
    for (int i = 0; i < 4; ++i)
        *(float4*)&As[tr * 4 + i][tc * 4] = make_float4(h[i][0], h[i][1], h[i][2], h[i][3]);
    __syncthreads();
    #pragma unroll
    for (int i = 0; i < 4; ++i)
        #pragma unroll
        for (int j = 0; j < 4; ++j) acc[i][j] = 0.f;
    for (int kc = 0; kc < 32; ++kc) {
        float4 a[4], w[4];
        #pragma unroll
        for (int i = 0; i < 4; ++i) a[i] = *(const float4*)&As[tr * 4 + i][kc * 4];
        #pragma unroll
        for (int kk = 0; kk < 4; ++kk) w[kk] = *(const float4*)&Wl[(kc * 4 + kk) * DIM + tc * 4];
        float af[4][4];
        #pragma unroll
        for (int i = 0; i < 4; ++i) {
            af[i][0] = a[i].x; af[i][1] = a[i].y; af[i][2] = a[i].z; af[i][3] = a[i].w;
        }
        #pragma unroll
        for (int kk = 0; kk < 4; ++kk) {
            float wv[4] = {w[kk].x, w[kk].y, w[kk].z, w[kk].w};
            #pragma unroll
            for (int i = 0; i < 4; ++i)
                #pragma unroll
                for (int j = 0; j < 4; ++j)
                    acc[i][j] = fmaf(af[i][kk], wv[j], acc[i][j]);
        }
    }
    float4 bv2 = ((const float4*)b2)[tc];
    float4* io4 = (float4*)io;
    #pragma unroll
    for (int ri = 0; ri < 4; ++ri) {
        int row = r0 + tr * 4 + ri;
        if (row < N) {
            float4 o = make_float4(acc[ri][0] + bv2.x, acc[ri][1] + bv2.y,
                                   acc[ri][2] + bv2.z, acc[ri][3] + bv2.w);
            io4[(size_t)row * 32 + tc] = o;
        }
    }
}

extern "C" void kernel_launch(void* const* d_in, const int* in_sizes, int n_in,
                              void* d_out, int out_size, void* d_ws, size_t ws_size,
                              hipStream_t stream) {
    const float* x  = (const float*)d_in[0];
    const int*   ei = (const int*)d_in[1];
    const float* W1 = (const float*)d_in[2];
    const float* b1 = (const float*)d_in[3];
    const float* W2 = (const float*)d_in[4];
    const float* b2 = (const float*)d_in[5];
    float* out = (float*)d_out;

    // primary ws layout: xb[12.8MB] | hpb[12.8MB] | sl16[1.28MB] | w1t | w2t | deg | cur | off | bsum
    const size_t xb_bytes  = (size_t)NNODES * DIM * 2;        // 12,800,000
    const size_t hp_bytes  = (size_t)NNODES * DIM * 2;        // 12,800,000
    const size_t sl_bytes  = (size_t)NEDGES * 2;              // 1,280,000
    const size_t wt_bytes  = (size_t)DIM * DIM * 2;           // 32,768
    const size_t deg_bytes = (size_t)NNODES * sizeof(int);    // 200,000
    const size_t off_bytes = (size_t)(NNODES + 4) * sizeof(int);
    const size_t bsum_bytes = (size_t)SCAN_BLK * sizeof(int) + 64;
    const size_t need_full = xb_bytes + hp_bytes + sl_bytes + 2 * wt_bytes
                           + 2 * deg_bytes + off_bytes + bsum_bytes;

    const size_t csr_ints = (size_t)(NNODES * 2 + (NNODES + 1) + NEDGES + 128);
    const size_t need_csr = csr_ints * sizeof(int);

    if (ws_size >= need_full) {
        char* p = (char*)d_ws;
        u16* xb   = (u16*)p;   p += xb_bytes;
        u16* hpb  = (u16*)p;   p += hp_bytes;
        u16* sl   = (u16*)p;   p += sl_bytes;
        u16* w1t  = (u16*)p;   p += wt_bytes;
        u16* w2t  = (u16*)p;   p += wt_bytes;
        int* deg  = (int*)p;   p += deg_bytes;
        int* cur  = (int*)p;   p += deg_bytes;
        int* off  = (int*)p;   p += off_bytes;
        int* bsum = (int*)p;

        prep_k<<<CVT_BLKS + CVTW_BLKS + DEG_BLKS, 256, 0, stream>>>(
            (const float4*)x, xb, W1, W2, w1t, deg);
        hist_k<<<(NEDGES + 255) / 256, 256, 0, stream>>>(ei, deg, NEDGES);
        scanA_k<<<SCAN_BLK, 256, 0, stream>>>(deg, bsum);
        scanC_k<<<SCAN_BLK, 256, 0, stream>>>(deg, bsum, off, cur);
        fill16_k<<<(NEDGES + 255) / 256, 256, 0, stream>>>(ei, cur, sl, NEDGES);
        gather_cs_k<<<NSLICE * ((NNODES + 127) / 128), 256, 0, stream>>>(xb, off, sl, hpb);
        mlp_mfma_k<<<(NNODES + 63) / 64, 256, 0, stream>>>(
            xb, hpb, out, w1t, b1, w2t, b2);
    } else if (ws_size >= need_csr) {
        int* deg = (int*)d_ws;
        int* cur = deg + NNODES;
        int* off = cur + NNODES;
        int* srclist = off + NNODES + 1;
        int* bsum = srclist + NEDGES;
        zero_k<<<(NNODES + 255) / 256, 256, 0, stream>>>(deg, NNODES);
        hist_k<<<(NEDGES + 255) / 256, 256, 0, stream>>>(ei, deg, NEDGES);
        scanA_k<<<SCAN_BLK, 256, 0, stream>>>(deg, bsum);
        scanC_k<<<SCAN_BLK, 256, 0, stream>>>(deg, bsum, off, cur);
        fill_k<<<(NEDGES + 255) / 256, 256, 0, stream>>>(ei, cur, srclist, NEDGES);
        gather_k<<<(NNODES * 32 + 255) / 256, 256, 0, stream>>>(
            (const float4*)x, off, srclist, (float4*)out);
        mlp_k<<<(NNODES + 31) / 32, 256, 0, stream>>>(out, W1, b1, W2, b2, NNODES);
    } else {
        int n4 = NNODES * DIM / 4;
        copy_k<<<(n4 + 255) / 256, 256, 0, stream>>>((const float4*)x, (float4*)out, n4);
        scatter_k<<<(NEDGES * 32 + 255) / 256, 256, 0, stream>>>((const float4*)x, ei, out, NEDGES);
        mlp_k<<<(NNODES + 31) / 32, 256, 0, stream>>>(out, W1, b1, W2, b2, NNODES);
    }
}

// Round 4
// 183.903 us; speedup vs baseline: 1.2108x; 1.2108x over previous
//
#include <hip/hip_runtime.h>

#define NNODES 50000
#define NEDGES 640000
#define DIM 128
#define SCAN_BLK 49   // ceil(50000 / 1024)

typedef unsigned short u16;
typedef __attribute__((ext_vector_type(8))) short short8;   // 8 bf16 (4 VGPRs)
typedef __attribute__((ext_vector_type(4))) float f32x4;

// ---------------- bf16 helpers ----------------
__device__ __forceinline__ unsigned int bf16rne(float f) {
    unsigned int u = __float_as_uint(f);
    return (u + 0x7FFFu + ((u >> 16) & 1u)) >> 16;   // RNE (no NaN inputs)
}
__device__ __forceinline__ float bflo(unsigned int p) { return __uint_as_float(p << 16); }
__device__ __forceinline__ float bfhi(unsigned int p) { return __uint_as_float(p & 0xFFFF0000u); }

// ---------------- fused prep: cvt x -> bf16 (row-major) | cvt W1,W2 -> bf16^T | head = -1 ----
#define CVT_BLKS   3125   // 800000 uint4 / 256
#define CVTW_BLKS  128    // 32768 / 256
#define HEAD_BLKS  196    // ceil(50000 / 256)
__global__ void prep_k(const float4* __restrict__ x4, uint4* __restrict__ xb4,
                       const float* __restrict__ W1, const float* __restrict__ W2,
                       u16* __restrict__ wt, int* __restrict__ head) {
    const int b = blockIdx.x, t = threadIdx.x;
    if (b < CVT_BLKS) {
        int i = b * 256 + t;                       // < 800000
        float4 a = x4[2 * i], c = x4[2 * i + 1];
        uint4 o;
        o.x = bf16rne(a.x) | (bf16rne(a.y) << 16);
        o.y = bf16rne(a.z) | (bf16rne(a.w) << 16);
        o.z = bf16rne(c.x) | (bf16rne(c.y) << 16);
        o.w = bf16rne(c.z) | (bf16rne(c.w) << 16);
        xb4[i] = o;
    } else if (b < CVT_BLKS + CVTW_BLKS) {
        int i = (b - CVT_BLKS) * 256 + t;          // < 32768
        const float* W = (i < DIM * DIM) ? W1 : W2;
        int li = i & (DIM * DIM - 1);
        int n = li >> 7, k = li & 127;
        wt[i] = (u16)bf16rne(W[k * DIM + n]);
    } else {
        int i = (b - CVT_BLKS - CVTW_BLKS) * 256 + t;
        if (i < NNODES) head[i] = -1;
    }
}

// ---------------- linked-list adjacency build ----------------
// nextsrc[e] = {src, prev_head}; head[dst] = e. Payload store is coalesced by e.
__global__ void fill_ll_k(const int* __restrict__ ei, int* __restrict__ head,
                          int2* __restrict__ nextsrc, int E) {
    int e = blockIdx.x * blockDim.x + threadIdx.x;
    if (e >= E) return;
    int src = ei[e];
    int dst = ei[E + e];
    int old = atomicExch(&head[dst], e);
    nextsrc[e] = make_int2(src, old);
}

// ---------------- fused gather + MFMA MLP ----------------
// Block = 64 nodes, 256 threads (4 waves x 16 rows). Gather phase: 8 lanes/node,
// 8 concurrent chains per wave, 2 rounds; aggregate (neighbors only) -> bf16 in
// wave-private LDS slab. MLP phase: layer1 A = x + agg via two MFMAs (linearity,
// R3-verified); LDS slab reused for the layer-2 activation buffer. No barriers
// (all LDS wave-private) -> waves overlap gather (VMEM) with MFMA (matrix pipe).
__launch_bounds__(256)
__global__ void gathermlp_k(const u16* __restrict__ xb, const int* __restrict__ head,
                            const int2* __restrict__ nextsrc, float* __restrict__ outp,
                            const u16* __restrict__ w1t, const float* __restrict__ b1,
                            const u16* __restrict__ w2t, const float* __restrict__ b2) {
    __shared__ __align__(16) u16 Hbuf[4][16][136];   // 17.4 KB, wave-private slabs

    const int tid = threadIdx.x;
    const int wv = tid >> 6, lane = tid & 63;
    const int quad = lane >> 4, msel = lane & 15;
    const int g8 = lane >> 3, l8 = lane & 7;
    const int rowbase = blockIdx.x * 64 + wv * 16;

    // ---- gather: rounds r=0,1; wave handles nodes rowbase + r*8 + g8 ----
    #pragma unroll
    for (int r = 0; r < 2; ++r) {
        int n = rowbase + r * 8 + g8;
        int nd = n < NNODES ? n : NNODES - 1;        // clamped dup walk; stores predicated later
        float a[16];
        #pragma unroll
        for (int i = 0; i < 16; ++i) a[i] = 0.f;
        int j = head[nd];
        while (j >= 0) {
            int2 p = nextsrc[j];
            const u16* row = xb + (size_t)p.x * DIM + l8 * 16;
            uint4 q0 = *(const uint4*)row;
            uint4 q1 = *(const uint4*)(row + 8);
            j = p.y;
            a[0]  += bflo(q0.x); a[1]  += bfhi(q0.x);
            a[2]  += bflo(q0.y); a[3]  += bfhi(q0.y);
            a[4]  += bflo(q0.z); a[5]  += bfhi(q0.z);
            a[6]  += bflo(q0.w); a[7]  += bfhi(q0.w);
            a[8]  += bflo(q1.x); a[9]  += bfhi(q1.x);
            a[10] += bflo(q1.y); a[11] += bfhi(q1.y);
            a[12] += bflo(q1.z); a[13] += bfhi(q1.z);
            a[14] += bflo(q1.w); a[15] += bfhi(q1.w);
        }
        uint4 o0, o1;
        o0.x = bf16rne(a[0])  | (bf16rne(a[1])  << 16);
        o0.y = bf16rne(a[2])  | (bf16rne(a[3])  << 16);
        o0.z = bf16rne(a[4])  | (bf16rne(a[5])  << 16);
        o0.w = bf16rne(a[6])  | (bf16rne(a[7])  << 16);
        o1.x = bf16rne(a[8])  | (bf16rne(a[9])  << 16);
        o1.y = bf16rne(a[10]) | (bf16rne(a[11]) << 16);
        o1.z = bf16rne(a[12]) | (bf16rne(a[13]) << 16);
        o1.w = bf16rne(a[14]) | (bf16rne(a[15]) << 16);
        *(uint4*)&Hbuf[wv][r * 8 + g8][l8 * 16]     = o0;
        *(uint4*)&Hbuf[wv][r * 8 + g8][l8 * 16 + 8] = o1;
    }
    // no __syncthreads: Hbuf[wv] is wave-private; wave-lockstep + in-order DS pipe suffice

    int rowA = rowbase + msel;
    if (rowA >= NNODES) rowA = NNODES - 1;

    f32x4 acc[8];
    #pragma unroll
    for (int t = 0; t < 8; ++t) acc[t] = (f32x4){0.f, 0.f, 0.f, 0.f};

    // ---- layer 1: (x + agg) W1 = xW1 + aggW1 ----
    #pragma unroll
    for (int it = 0; it < 4; ++it) {
        short8 xfr = *(const short8*)(xb + (size_t)rowA * DIM + it * 32 + quad * 8);
        short8 gfr = *(const short8*)&Hbuf[wv][msel][it * 32 + quad * 8];
        #pragma unroll
        for (int t = 0; t < 8; ++t) {
            short8 bfr = *(const short8*)(w1t + (size_t)(t * 16 + msel) * DIM + it * 32 + quad * 8);
            acc[t] = __builtin_amdgcn_mfma_f32_16x16x32_bf16(xfr, bfr, acc[t], 0, 0, 0);
            acc[t] = __builtin_amdgcn_mfma_f32_16x16x32_bf16(gfr, bfr, acc[t], 0, 0, 0);
        }
    }

    // epilogue 1: +b1, relu, bf16 -> Hbuf reused as layer-2 A buffer (wave-private,
    // ordered after the gfr reads by data dependence + in-order per-wave DS pipe)
    #pragma unroll
    for (int t = 0; t < 8; ++t) {
        float bb = b1[t * 16 + msel];
        #pragma unroll
        for (int r = 0; r < 4; ++r) {
            float v = fmaxf(acc[t][r] + bb, 0.f);
            Hbuf[wv][quad * 4 + r][t * 16 + msel] = (u16)bf16rne(v);
        }
    }

    // ---- layer 2 ----
    #pragma unroll
    for (int t = 0; t < 8; ++t) acc[t] = (f32x4){0.f, 0.f, 0.f, 0.f};
    #pragma unroll
    for (int it = 0; it < 4; ++it) {
        short8 afr = *(const short8*)&Hbuf[wv][msel][it * 32 + quad * 8];
        #pragma unroll
        for (int t = 0; t < 8; ++t) {
            short8 bfr = *(const short8*)(w2t + (size_t)(t * 16 + msel) * DIM + it * 32 + quad * 8);
            acc[t] = __builtin_amdgcn_mfma_f32_16x16x32_bf16(afr, bfr, acc[t], 0, 0, 0);
        }
    }

    // epilogue 2: +b2, store f32
    #pragma unroll
    for (int t = 0; t < 8; ++t) {
        float bb = b2[t * 16 + msel];
        #pragma unroll
        for (int r = 0; r < 4; ++r) {
            int row = rowbase + quad * 4 + r;
            if (row < NNODES)
                outp[(size_t)row * DIM + t * 16 + msel] = acc[t][r] + bb;
        }
    }
}

// ================= fallback paths (smaller ws) =================

__global__ void zero_k(int* __restrict__ p, int n) {
    int i = blockIdx.x * blockDim.x + threadIdx.x;
    if (i < n) p[i] = 0;
}

__global__ void hist_k(const int* __restrict__ ei, int* __restrict__ deg, int E) {
    int e = blockIdx.x * blockDim.x + threadIdx.x;
    if (e < E) atomicAdd(&deg[ei[E + e]], 1);
}

__global__ void scanA_k(const int* __restrict__ deg, int* __restrict__ bsum) {
    const int t = threadIdx.x, b = blockIdx.x;
    const int base = b * 1024 + t * 4;
    int4 v = make_int4(0, 0, 0, 0);
    if (base < NNODES) v = *(const int4*)&deg[base];
    int s = v.x + v.y + v.z + v.w;
    #pragma unroll
    for (int d = 32; d > 0; d >>= 1) s += __shfl_down(s, d, 64);
    __shared__ int ws[4];
    if ((t & 63) == 0) ws[t >> 6] = s;
    __syncthreads();
    if (t == 0) bsum[b] = ws[0] + ws[1] + ws[2] + ws[3];
}

__global__ void scanC_k(const int* __restrict__ deg, const int* __restrict__ bsum,
                        int* __restrict__ off, int* __restrict__ cur) {
    __shared__ int ws[4];
    __shared__ int sbase;
    const int t = threadIdx.x, b = blockIdx.x;
    if (t < 64) {
        int v = (t < SCAN_BLK && t < b) ? bsum[t] : 0;
        #pragma unroll
        for (int d = 32; d > 0; d >>= 1) v += __shfl_down(v, d, 64);
        if (t == 0) sbase = v;
    }
    const int base = b * 1024 + t * 4;
    int4 v = make_int4(0, 0, 0, 0);
    if (base < NNODES) v = *(const int4*)&deg[base];
    const int s = v.x + v.y + v.z + v.w;
    const int lane = t & 63, w = t >> 6;
    int sv = s;
    #pragma unroll
    for (int d = 1; d < 64; d <<= 1) {
        int u = __shfl_up(sv, d, 64);
        if (lane >= d) sv += u;
    }
    if (lane == 63) ws[w] = sv;
    __syncthreads();
    int wbase = 0;
    #pragma unroll
    for (int i = 0; i < 4; ++i) if (i < w) wbase += ws[i];
    int ex = sbase + wbase + (sv - s);
    if (base < NNODES) {
        int4 o;
        o.x = ex;
        o.y = o.x + v.x;
        o.z = o.y + v.y;
        o.w = o.z + v.z;
        *(int4*)&off[base] = o;
        *(int4*)&cur[base] = o;
    }
    if (b == 0 && t == 0) off[NNODES] = NEDGES;
}

__global__ void fill_k(const int* __restrict__ ei, int* __restrict__ cur,
                       int* __restrict__ srclist, int E) {
    int e = blockIdx.x * blockDim.x + threadIdx.x;
    if (e >= E) return;
    int src = ei[e];
    int dst = ei[E + e];
    int pos = atomicAdd(&cur[dst], 1);
    srclist[pos] = src;
}

__global__ void gather_k(const float4* __restrict__ x4, const int* __restrict__ off,
                         const int* __restrict__ srclist, float4* __restrict__ hp4) {
    int t = blockIdx.x * blockDim.x + threadIdx.x;
    int node = t >> 5;
    if (node >= NNODES) return;
    int lane = t & 31;
    float4 acc = x4[(size_t)node * 32 + lane];
    int beg = off[node], end = off[node + 1];
    for (int j = beg; j < end; ++j) {
        int s = srclist[j];
        float4 v = x4[(size_t)s * 32 + lane];
        acc.x += v.x; acc.y += v.y; acc.z += v.z; acc.w += v.w;
    }
    hp4[(size_t)node * 32 + lane] = acc;
}

__global__ void copy_k(const float4* __restrict__ src, float4* __restrict__ dst, int n4) {
    int i = blockIdx.x * blockDim.x + threadIdx.x;
    if (i < n4) dst[i] = src[i];
}

__global__ void scatter_k(const float4* __restrict__ x4, const int* __restrict__ ei,
                          float* __restrict__ hp, int E) {
    int t = blockIdx.x * blockDim.x + threadIdx.x;
    int e = t >> 5;
    if (e >= E) return;
    int lane = t & 31;
    int src = ei[e];
    int dst = ei[E + e];
    float4 v = x4[(size_t)src * 32 + lane];
    float* p = hp + (size_t)dst * DIM + lane * 4;
    unsafeAtomicAdd(p + 0, v.x);
    unsafeAtomicAdd(p + 1, v.y);
    unsafeAtomicAdd(p + 2, v.z);
    unsafeAtomicAdd(p + 3, v.w);
}

__launch_bounds__(256)
__global__ void mlp_k(float* __restrict__ io,
                      const float* __restrict__ W1, const float* __restrict__ b1,
                      const float* __restrict__ W2, const float* __restrict__ b2,
                      int N) {
    __shared__ float Wl[DIM * DIM];
    __shared__ float As[32][DIM];
    const int tid = threadIdx.x;
    const int r0 = blockIdx.x * 32;
    const int tc = tid & 31;
    const int tr = tid >> 5;
    {
        const float4* w4 = (const float4*)W1;
        float4* wl4 = (float4*)Wl;
        #pragma unroll
        for (int i = 0; i < 16; ++i) wl4[tid + i * 256] = w4[tid + i * 256];
    }
    {
        const float4* io4 = (const float4*)io;
        float4* as4 = (float4*)As;
        #pragma unroll
        for (int i = 0; i < 4; ++i) {
            int p = tid + i * 256;
            int row = p >> 5;
            float4 v = make_float4(0.f, 0.f, 0.f, 0.f);
            if (r0 + row < N) v = io4[(size_t)(r0 + row) * 32 + (p & 31)];
            as4[p] = v;
        }
    }
    __syncthreads();
    float acc[4][4];
    #pragma unroll
    for (int i = 0; i < 4; ++i)
        #pragma unroll
        for (int j = 0; j < 4; ++j) acc[i][j] = 0.f;
    for (int kc = 0; kc < 32; ++kc) {
        float4 a[4], w[4];
        #pragma unroll
        for (int i = 0; i < 4; ++i) a[i] = *(const float4*)&As[tr * 4 + i][kc * 4];
        #pragma unroll
        for (int kk = 0; kk < 4; ++kk) w[kk] = *(const float4*)&Wl[(kc * 4 + kk) * DIM + tc * 4];
        float af[4][4];
        #pragma unroll
        for (int i = 0; i < 4; ++i) {
            af[i][0] = a[i].x; af[i][1] = a[i].y; af[i][2] = a[i].z; af[i][3] = a[i].w;
        }
        #pragma unroll
        for (int kk = 0; kk < 4; ++kk) {
            float wv[4] = {w[kk].x, w[kk].y, w[kk].z, w[kk].w};
            #pragma unroll
            for (int i = 0; i < 4; ++i)
                #pragma unroll
                for (int j = 0; j < 4; ++j)
                    acc[i][j] = fmaf(af[i][kk], wv[j], acc[i][j]);
        }
    }
    float4 bv1 = ((const float4*)b1)[tc];
    float h[4][4];
    #pragma unroll
    for (int i = 0; i < 4; ++i) {
        h[i][0] = fmaxf(acc[i][0] + bv1.x, 0.f);
        h[i][1] = fmaxf(acc[i][1] + bv1.y, 0.f);
        h[i][2] = fmaxf(acc[i][2] + bv1.z, 0.f);
        h[i][3] = fmaxf(acc[i][3] + bv1.w, 0.f);
    }
    __syncthreads();
    {
        const float4* w4 = (const float4*)W2;
        float4* wl4 = (float4*)Wl;
        #pragma unroll
        for (int i = 0; i < 16; ++i) wl4[tid + i * 256] = w4[tid + i * 256];
    }
    #pragma unroll
    for (int i = 0; i < 4; ++i)
        *(float4*)&As[tr * 4 + i][tc * 4] = make_float4(h[i][0], h[i][1], h[i][2], h[i][3]);
    __syncthreads();
    #pragma unroll
    for (int i = 0; i < 4; ++i)
        #pragma unroll
        for (int j = 0; j < 4; ++j) acc[i][j] = 0.f;
    for (int kc = 0; kc < 32; ++kc) {
        float4 a[4], w[4];
        #pragma unroll
        for (int i = 0; i < 4; ++i) a[i] = *(const float4*)&As[tr * 4 + i][kc * 4];
        #pragma unroll
        for (int kk = 0; kk < 4; ++kk) w[kk] = *(const float4*)&Wl[(kc * 4 + kk) * DIM + tc * 4];
        float af[4][4];
        #pragma unroll
        for (int i = 0; i < 4; ++i) {
            af[i][0] = a[i].x; af[i][1] = a[i].y; af[i][2] = a[i].z; af[i][3] = a[i].w;
        }
        #pragma unroll
        for (int kk = 0; kk < 4; ++kk) {
            float wv[4] = {w[kk].x, w[kk].y, w[kk].z, w[kk].w};
            #pragma unroll
            for (int i = 0; i < 4; ++i)
                #pragma unroll
                for (int j = 0; j < 4; ++j)
                    acc[i][j] = fmaf(af[i][kk], wv[j], acc[i][j]);
        }
    }
    float4 bv2 = ((const float4*)b2)[tc];
    float4* io4 = (float4*)io;
    #pragma unroll
    for (int ri = 0; ri < 4; ++ri) {
        int row = r0 + tr * 4 + ri;
        if (row < N) {
            float4 o = make_float4(acc[ri][0] + bv2.x, acc[ri][1] + bv2.y,
                                   acc[ri][2] + bv2.z, acc[ri][3] + bv2.w);
            io4[(size_t)row * 32 + tc] = o;
        }
    }
}

extern "C" void kernel_launch(void* const* d_in, const int* in_sizes, int n_in,
                              void* d_out, int out_size, void* d_ws, size_t ws_size,
                              hipStream_t stream) {
    const float* x  = (const float*)d_in[0];
    const int*   ei = (const int*)d_in[1];
    const float* W1 = (const float*)d_in[2];
    const float* b1 = (const float*)d_in[3];
    const float* W2 = (const float*)d_in[4];
    const float* b2 = (const float*)d_in[5];
    float* out = (float*)d_out;

    // primary ws layout: xb[12.8MB] | head[200KB] | nextsrc[640000 int2] | w1t | w2t
    const size_t xb_bytes   = (size_t)NNODES * DIM * 2;       // 12,800,000
    const size_t head_bytes = (size_t)NNODES * sizeof(int);   // 200,000
    const size_t ns_bytes   = (size_t)NEDGES * sizeof(int2);  // 5,120,000
    const size_t wt_bytes   = (size_t)DIM * DIM * 2;          // 32,768
    const size_t need_full  = xb_bytes + head_bytes + ns_bytes + 2 * wt_bytes;

    const size_t csr_ints = (size_t)(NNODES * 2 + (NNODES + 1) + NEDGES + 128);
    const size_t need_csr = csr_ints * sizeof(int);

    if (ws_size >= need_full) {
        char* p = (char*)d_ws;
        uint4* xb4  = (uint4*)p;                 p += xb_bytes;
        int*   head = (int*)p;                   p += head_bytes;
        int2*  nextsrc = (int2*)p;               p += ns_bytes;
        u16*   w1t  = (u16*)p;
        u16*   w2t  = w1t + DIM * DIM;

        prep_k<<<CVT_BLKS + CVTW_BLKS + HEAD_BLKS, 256, 0, stream>>>(
            (const float4*)x, xb4, W1, W2, w1t, head);
        fill_ll_k<<<(NEDGES + 255) / 256, 256, 0, stream>>>(ei, head, nextsrc, NEDGES);
        gathermlp_k<<<(NNODES + 63) / 64, 256, 0, stream>>>(
            (const u16*)xb4, head, nextsrc, out, w1t, b1, w2t, b2);
    } else if (ws_size >= need_csr) {
        int* deg = (int*)d_ws;
        int* cur = deg + NNODES;
        int* off = cur + NNODES;
        int* srclist = off + NNODES + 1;
        int* bsum = srclist + NEDGES;
        zero_k<<<(NNODES + 255) / 256, 256, 0, stream>>>(deg, NNODES);
        hist_k<<<(NEDGES + 255) / 256, 256, 0, stream>>>(ei, deg, NEDGES);
        scanA_k<<<SCAN_BLK, 256, 0, stream>>>(deg, bsum);
        scanC_k<<<SCAN_BLK, 256, 0, stream>>>(deg, bsum, off, cur);
        fill_k<<<(NEDGES + 255) / 256, 256, 0, stream>>>(ei, cur, srclist, NEDGES);
        gather_k<<<(NNODES * 32 + 255) / 256, 256, 0, stream>>>(
            (const float4*)x, off, srclist, (float4*)out);
        mlp_k<<<(NNODES + 31) / 32, 256, 0, stream>>>(out, W1, b1, W2, b2, NNODES);
    } else {
        int n4 = NNODES * DIM / 4;
        copy_k<<<(n4 + 255) / 256, 256, 0, stream>>>((const float4*)x, (float4*)out, n4);
        scatter_k<<<(NEDGES * 32 + 255) / 256, 256, 0, stream>>>((const float4*)x, ei, out, NEDGES);
        mlp_k<<<(NNODES + 31) / 32, 256, 0, stream>>>(out, W1, b1, W2, b2, NNODES);
    }
}

// Round 5
// 179.267 us; speedup vs baseline: 1.2421x; 1.0259x over previous
//
#include <hip/hip_runtime.h>

#define NNODES 50000
#define NEDGES 640000
#define DIM 128
#define SCAN_BLK 49   // ceil(50000 / 1024)
#define CAP 64        // bucket capacity per node (Poisson(12.8) max deg ~40; LL overflow path)

typedef unsigned short u16;
typedef __attribute__((ext_vector_type(8))) short short8;   // 8 bf16 (4 VGPRs)
typedef __attribute__((ext_vector_type(4))) float f32x4;

// ---------------- bf16 helpers ----------------
__device__ __forceinline__ unsigned int bf16rne(float f) {
    unsigned int u = __float_as_uint(f);
    return (u + 0x7FFFu + ((u >> 16) & 1u)) >> 16;   // RNE (no NaN inputs)
}
__device__ __forceinline__ float bflo(unsigned int p) { return __uint_as_float(p << 16); }
__device__ __forceinline__ float bfhi(unsigned int p) { return __uint_as_float(p & 0xFFFF0000u); }

// ---------------- fused prep: cvt x -> bf16 | cvt W1,W2 -> bf16^T | cnt=0, head=-1 ----------
#define CVT_BLKS   3125   // 800000 uint4 / 256
#define CVTW_BLKS  128    // 32768 / 256
#define INIT_BLKS  391    // ceil(100000 / 256): cnt[50000] + head[50000]
__global__ void prep_k(const float4* __restrict__ x4, uint4* __restrict__ xb4,
                       const float* __restrict__ W1, const float* __restrict__ W2,
                       u16* __restrict__ wt, int* __restrict__ cnt, int* __restrict__ head) {
    const int b = blockIdx.x, t = threadIdx.x;
    if (b < CVT_BLKS) {
        int i = b * 256 + t;                       // < 800000
        float4 a = x4[2 * i], c = x4[2 * i + 1];
        uint4 o;
        o.x = bf16rne(a.x) | (bf16rne(a.y) << 16);
        o.y = bf16rne(a.z) | (bf16rne(a.w) << 16);
        o.z = bf16rne(c.x) | (bf16rne(c.y) << 16);
        o.w = bf16rne(c.z) | (bf16rne(c.w) << 16);
        xb4[i] = o;
    } else if (b < CVT_BLKS + CVTW_BLKS) {
        int i = (b - CVT_BLKS) * 256 + t;          // < 32768
        const float* W = (i < DIM * DIM) ? W1 : W2;
        int li = i & (DIM * DIM - 1);
        int n = li >> 7, k = li & 127;
        wt[i] = (u16)bf16rne(W[k * DIM + n]);
    } else {
        int i = (b - CVT_BLKS - CVTW_BLKS) * 256 + t;
        if (i < NNODES) cnt[i] = 0;
        else if (i < 2 * NNODES) head[i - NNODES] = -1;
    }
}

// ---------------- padded-CSR bucket build (no scan needed) ----------------
// sl[dst*CAP + pos] = src via atomicAdd counter; rare overflow -> linked list.
__global__ void fillpad_k(const int* __restrict__ ei, int* __restrict__ cnt,
                          u16* __restrict__ sl, int* __restrict__ head,
                          int2* __restrict__ nextsrc, int E) {
    int e = blockIdx.x * blockDim.x + threadIdx.x;
    if (e >= E) return;
    int src = ei[e];
    int dst = ei[E + e];
    int pos = atomicAdd(&cnt[dst], 1);
    if (pos < CAP) {
        sl[(size_t)dst * CAP + pos] = (u16)src;
    } else {
        int old = atomicExch(&head[dst], e);
        nextsrc[e] = make_int2(src, old);
    }
}

// ---------------- fused gather + MFMA MLP ----------------
// Block = 64 nodes, 256 threads (4 waves x 16 rows). Gather phase: 8 lanes/node,
// 2 rounds; bucket loop has a KNOWN trip count and fully INDEPENDENT row loads
// (no chain dependency) -> deep VMEM pipelining per wave. Aggregate -> bf16 in
// wave-private LDS slab. MLP: layer1 A = x + agg via two MFMAs (linearity,
// verified R3/R4); LDS slab reused for layer-2 activations. No barriers.
__launch_bounds__(256)
__global__ void gathermlp_k(const u16* __restrict__ xb, const int* __restrict__ cnt,
                            const u16* __restrict__ sl, const int* __restrict__ head,
                            const int2* __restrict__ nextsrc, float* __restrict__ outp,
                            const u16* __restrict__ w1t, const float* __restrict__ b1,
                            const u16* __restrict__ w2t, const float* __restrict__ b2) {
    __shared__ __align__(16) u16 Hbuf[4][16][136];   // 17.4 KB, wave-private slabs

    const int tid = threadIdx.x;
    const int wv = tid >> 6, lane = tid & 63;
    const int quad = lane >> 4, msel = lane & 15;
    const int g8 = lane >> 3, l8 = lane & 7;
    const int rowbase = blockIdx.x * 64 + wv * 16;

    // ---- gather: rounds r=0,1; wave handles nodes rowbase + r*8 + g8 ----
    #pragma unroll
    for (int r = 0; r < 2; ++r) {
        int n = rowbase + r * 8 + g8;
        int nd = n < NNODES ? n : NNODES - 1;        // clamped dup walk; stores predicated later
        float a[16];
        #pragma unroll
        for (int i = 0; i < 16; ++i) a[i] = 0.f;

        const int cn = cnt[nd];
        const int kb = cn < CAP ? cn : CAP;
        const u16* __restrict__ bp = sl + (size_t)nd * CAP;
        #pragma unroll 2
        for (int j = 0; j < kb; ++j) {
            int srcn = bp[j];
            const u16* row = xb + (size_t)srcn * DIM + l8 * 16;
            uint4 q0 = *(const uint4*)row;
            uint4 q1 = *(const uint4*)(row + 8);
            a[0]  += bflo(q0.x); a[1]  += bfhi(q0.x);
            a[2]  += bflo(q0.y); a[3]  += bfhi(q0.y);
            a[4]  += bflo(q0.z); a[5]  += bfhi(q0.z);
            a[6]  += bflo(q0.w); a[7]  += bfhi(q0.w);
            a[8]  += bflo(q1.x); a[9]  += bfhi(q1.x);
            a[10] += bflo(q1.y); a[11] += bfhi(q1.y);
            a[12] += bflo(q1.z); a[13] += bfhi(q1.z);
            a[14] += bflo(q1.w); a[15] += bfhi(q1.w);
        }
        if (cn > CAP) {                              // rare overflow: walk LL remainder
            int j = head[nd];
            while (j >= 0) {
                int2 p = nextsrc[j];
                const u16* row = xb + (size_t)p.x * DIM + l8 * 16;
                uint4 q0 = *(const uint4*)row;
                uint4 q1 = *(const uint4*)(row + 8);
                j = p.y;
                a[0]  += bflo(q0.x); a[1]  += bfhi(q0.x);
                a[2]  += bflo(q0.y); a[3]  += bfhi(q0.y);
                a[4]  += bflo(q0.z); a[5]  += bfhi(q0.z);
                a[6]  += bflo(q0.w); a[7]  += bfhi(q0.w);
                a[8]  += bflo(q1.x); a[9]  += bfhi(q1.x);
                a[10] += bflo(q1.y); a[11] += bfhi(q1.y);
                a[12] += bflo(q1.z); a[13] += bfhi(q1.z);
                a[14] += bflo(q1.w); a[15] += bfhi(q1.w);
            }
        }
        uint4 o0, o1;
        o0.x = bf16rne(a[0])  | (bf16rne(a[1])  << 16);
        o0.y = bf16rne(a[2])  | (bf16rne(a[3])  << 16);
        o0.z = bf16rne(a[4])  | (bf16rne(a[5])  << 16);
        o0.w = bf16rne(a[6])  | (bf16rne(a[7])  << 16);
        o1.x = bf16rne(a[8])  | (bf16rne(a[9])  << 16);
        o1.y = bf16rne(a[10]) | (bf16rne(a[11]) << 16);
        o1.z = bf16rne(a[12]) | (bf16rne(a[13]) << 16);
        o1.w = bf16rne(a[14]) | (bf16rne(a[15]) << 16);
        *(uint4*)&Hbuf[wv][r * 8 + g8][l8 * 16]     = o0;
        *(uint4*)&Hbuf[wv][r * 8 + g8][l8 * 16 + 8] = o1;
    }
    // no __syncthreads: Hbuf[wv] is wave-private; per-wave in-order DS pipe suffices

    int rowA = rowbase + msel;
    if (rowA >= NNODES) rowA = NNODES - 1;

    f32x4 acc[8];
    #pragma unroll
    for (int t = 0; t < 8; ++t) acc[t] = (f32x4){0.f, 0.f, 0.f, 0.f};

    // ---- layer 1: (x + agg) W1 = xW1 + aggW1 ----
    #pragma unroll
    for (int it = 0; it < 4; ++it) {
        short8 xfr = *(const short8*)(xb + (size_t)rowA * DIM + it * 32 + quad * 8);
        short8 gfr = *(const short8*)&Hbuf[wv][msel][it * 32 + quad * 8];
        #pragma unroll
        for (int t = 0; t < 8; ++t) {
            short8 bfr = *(const short8*)(w1t + (size_t)(t * 16 + msel) * DIM + it * 32 + quad * 8);
            acc[t] = __builtin_amdgcn_mfma_f32_16x16x32_bf16(xfr, bfr, acc[t], 0, 0, 0);
            acc[t] = __builtin_amdgcn_mfma_f32_16x16x32_bf16(gfr, bfr, acc[t], 0, 0, 0);
        }
    }

    // epilogue 1: +b1, relu, bf16 -> Hbuf reused as layer-2 A buffer
    #pragma unroll
    for (int t = 0; t < 8; ++t) {
        float bb = b1[t * 16 + msel];
        #pragma unroll
        for (int r = 0; r < 4; ++r) {
            float v = fmaxf(acc[t][r] + bb, 0.f);
            Hbuf[wv][quad * 4 + r][t * 16 + msel] = (u16)bf16rne(v);
        }
    }

    // ---- layer 2 ----
    #pragma unroll
    for (int t = 0; t < 8; ++t) acc[t] = (f32x4){0.f, 0.f, 0.f, 0.f};
    #pragma unroll
    for (int it = 0; it < 4; ++it) {
        short8 afr = *(const short8*)&Hbuf[wv][msel][it * 32 + quad * 8];
        #pragma unroll
        for (int t = 0; t < 8; ++t) {
            short8 bfr = *(const short8*)(w2t + (size_t)(t * 16 + msel) * DIM + it * 32 + quad * 8);
            acc[t] = __builtin_amdgcn_mfma_f32_16x16x32_bf16(afr, bfr, acc[t], 0, 0, 0);
        }
    }

    // epilogue 2: +b2, store f32
    #pragma unroll
    for (int t = 0; t < 8; ++t) {
        float bb = b2[t * 16 + msel];
        #pragma unroll
        for (int r = 0; r < 4; ++r) {
            int row = rowbase + quad * 4 + r;
            if (row < NNODES)
                outp[(size_t)row * DIM + t * 16 + msel] = acc[t][r] + bb;
        }
    }
}

// ================= fallback paths (smaller ws) =================

__global__ void zero_k(int* __restrict__ p, int n) {
    int i = blockIdx.x * blockDim.x + threadIdx.x;
    if (i < n) p[i] = 0;
}

__global__ void hist_k(const int* __restrict__ ei, int* __restrict__ deg, int E) {
    int e = blockIdx.x * blockDim.x + threadIdx.x;
    if (e < E) atomicAdd(&deg[ei[E + e]], 1);
}

__global__ void scanA_k(const int* __restrict__ deg, int* __restrict__ bsum) {
    const int t = threadIdx.x, b = blockIdx.x;
    const int base = b * 1024 + t * 4;
    int4 v = make_int4(0, 0, 0, 0);
    if (base < NNODES) v = *(const int4*)&deg[base];
    int s = v.x + v.y + v.z + v.w;
    #pragma unroll
    for (int d = 32; d > 0; d >>= 1) s += __shfl_down(s, d, 64);
    __shared__ int ws[4];
    if ((t & 63) == 0) ws[t >> 6] = s;
    __syncthreads();
    if (t == 0) bsum[b] = ws[0] + ws[1] + ws[2] + ws[3];
}

__global__ void scanC_k(const int* __restrict__ deg, const int* __restrict__ bsum,
                        int* __restrict__ off, int* __restrict__ cur) {
    __shared__ int ws[4];
    __shared__ int sbase;
    const int t = threadIdx.x, b = blockIdx.x;
    if (t < 64) {
        int v = (t < SCAN_BLK && t < b) ? bsum[t] : 0;
        #pragma unroll
        for (int d = 32; d > 0; d >>= 1) v += __shfl_down(v, d, 64);
        if (t == 0) sbase = v;
    }
    const int base = b * 1024 + t * 4;
    int4 v = make_int4(0, 0, 0, 0);
    if (base < NNODES) v = *(const int4*)&deg[base];
    const int s = v.x + v.y + v.z + v.w;
    const int lane = t & 63, w = t >> 6;
    int sv = s;
    #pragma unroll
    for (int d = 1; d < 64; d <<= 1) {
        int u = __shfl_up(sv, d, 64);
        if (lane >= d) sv += u;
    }
    if (lane == 63) ws[w] = sv;
    __syncthreads();
    int wbase = 0;
    #pragma unroll
    for (int i = 0; i < 4; ++i) if (i < w) wbase += ws[i];
    int ex = sbase + wbase + (sv - s);
    if (base < NNODES) {
        int4 o;
        o.x = ex;
        o.y = o.x + v.x;
        o.z = o.y + v.y;
        o.w = o.z + v.z;
        *(int4*)&off[base] = o;
        *(int4*)&cur[base] = o;
    }
    if (b == 0 && t == 0) off[NNODES] = NEDGES;
}

__global__ void fill_k(const int* __restrict__ ei, int* __restrict__ cur,
                       int* __restrict__ srclist, int E) {
    int e = blockIdx.x * blockDim.x + threadIdx.x;
    if (e >= E) return;
    int src = ei[e];
    int dst = ei[E + e];
    int pos = atomicAdd(&cur[dst], 1);
    srclist[pos] = src;
}

__global__ void gather_k(const float4* __restrict__ x4, const int* __restrict__ off,
                         const int* __restrict__ srclist, float4* __restrict__ hp4) {
    int t = blockIdx.x * blockDim.x + threadIdx.x;
    int node = t >> 5;
    if (node >= NNODES) return;
    int lane = t & 31;
    float4 acc = x4[(size_t)node * 32 + lane];
    int beg = off[node], end = off[node + 1];
    for (int j = beg; j < end; ++j) {
        int s = srclist[j];
        float4 v = x4[(size_t)s * 32 + lane];
        acc.x += v.x; acc.y += v.y; acc.z += v.z; acc.w += v.w;
    }
    hp4[(size_t)node * 32 + lane] = acc;
}

__global__ void copy_k(const float4* __restrict__ src, float4* __restrict__ dst, int n4) {
    int i = blockIdx.x * blockDim.x + threadIdx.x;
    if (i < n4) dst[i] = src[i];
}

__global__ void scatter_k(const float4* __restrict__ x4, const int* __restrict__ ei,
                          float* __restrict__ hp, int E) {
    int t = blockIdx.x * blockDim.x + threadIdx.x;
    int e = t >> 5;
    if (e >= E) return;
    int lane = t & 31;
    int src = ei[e];
    int dst = ei[E + e];
    float4 v = x4[(size_t)src * 32 + lane];
    float* p = hp + (size_t)dst * DIM + lane * 4;
    unsafeAtomicAdd(p + 0, v.x);
    unsafeAtomicAdd(p + 1, v.y);
    unsafeAtomicAdd(p + 2, v.z);
    unsafeAtomicAdd(p + 3, v.w);
}

__launch_bounds__(256)
__global__ void mlp_k(float* __restrict__ io,
                      const float* __restrict__ W1, const float* __restrict__ b1,
                      const float* __restrict__ W2, const float* __restrict__ b2,
                      int N) {
    __shared__ float Wl[DIM * DIM];
    __shared__ float As[32][DIM];
    const int tid = threadIdx.x;
    const int r0 = blockIdx.x * 32;
    const int tc = tid & 31;
    const int tr = tid >> 5;
    {
        const float4* w4 = (const float4*)W1;
        float4* wl4 = (float4*)Wl;
        #pragma unroll
        for (int i = 0; i < 16; ++i) wl4[tid + i * 256] = w4[tid + i * 256];
    }
    {
        const float4* io4 = (const float4*)io;
        float4* as4 = (float4*)As;
        #pragma unroll
        for (int i = 0; i < 4; ++i) {
            int p = tid + i * 256;
            int row = p >> 5;
            float4 v = make_float4(0.f, 0.f, 0.f, 0.f);
            if (r0 + row < N) v = io4[(size_t)(r0 + row) * 32 + (p & 31)];
            as4[p] = v;
        }
    }
    __syncthreads();
    float acc[4][4];
    #pragma unroll
    for (int i = 0; i < 4; ++i)
        #pragma unroll
        for (int j = 0; j < 4; ++j) acc[i][j] = 0.f;
    for (int kc = 0; kc < 32; ++kc) {
        float4 a[4], w[4];
        #pragma unroll
        for (int i = 0; i < 4; ++i) a[i] = *(const float4*)&As[tr * 4 + i][kc * 4];
        #pragma unroll
        for (int kk = 0; kk < 4; ++kk) w[kk] = *(const float4*)&Wl[(kc * 4 + kk) * DIM + tc * 4];
        float af[4][4];
        #pragma unroll
        for (int i = 0; i < 4; ++i) {
            af[i][0] = a[i].x; af[i][1] = a[i].y; af[i][2] = a[i].z; af[i][3] = a[i].w;
        }
        #pragma unroll
        for (int kk = 0; kk < 4; ++kk) {
            float wv[4] = {w[kk].x, w[kk].y, w[kk].z, w[kk].w};
            #pragma unroll
            for (int i = 0; i < 4; ++i)
                #pragma unroll
                for (int j = 0; j < 4; ++j)
                    acc[i][j] = fmaf(af[i][kk], wv[j], acc[i][j]);
        }
    }
    float4 bv1 = ((const float4*)b1)[tc];
    float h[4][4];
    #pragma unroll
    for (int i = 0; i < 4; ++i) {
        h[i][0] = fmaxf(acc[i][0] + bv1.x, 0.f);
        h[i][1] = fmaxf(acc[i][1] + bv1.y, 0.f);
        h[i][2] = fmaxf(acc[i][2] + bv1.z, 0.f);
        h[i][3] = fmaxf(acc[i][3] + bv1.w, 0.f);
    }
    __syncthreads();
    {
        const float4* w4 = (const float4*)W2;
        float4* wl4 = (float4*)Wl;
        #pragma unroll
        for (int i = 0; i < 16; ++i) wl4[tid + i * 256] = w4[tid + i * 256];
    }
    #pragma unroll
    for (int i = 0; i < 4; ++i)
        *(float4*)&As[tr * 4 + i][tc * 4] = make_float4(h[i][0], h[i][1], h[i][2], h[i][3]);
    __syncthreads();
    #pragma unroll
    for (int i = 0; i < 4; ++i)
        #pragma unroll
        for (int j = 0; j < 4; ++j) acc[i][j] = 0.f;
    for (int kc = 0; kc < 32; ++kc) {
        float4 a[4], w[4];
        #pragma unroll
        for (int i = 0; i < 4; ++i) a[i] = *(const float4*)&As[tr * 4 + i][kc * 4];
        #pragma unroll
        for (int kk = 0; kk < 4; ++kk) w[kk] = *(const float4*)&Wl[(kc * 4 + kk) * DIM + tc * 4];
        float af[4][4];
        #pragma unroll
        for (int i = 0; i < 4; ++i) {
            af[i][0] = a[i].x; af[i][1] = a[i].y; af[i][2] = a[i].z; af[i][3] = a[i].w;
        }
        #pragma unroll
        for (int kk = 0; kk < 4; ++kk) {
            float wv[4] = {w[kk].x, w[kk].y, w[kk].z, w[kk].w};
            #pragma unroll
            for (int i = 0; i < 4; ++i)
                #pragma unroll
                for (int j = 0; j < 4; ++j)
                    acc[i][j] = fmaf(af[i][kk], wv[j], acc[i][j]);
        }
    }
    float4 bv2 = ((const float4*)b2)[tc];
    float4* io4 = (float4*)io;
    #pragma unroll
    for (int ri = 0; ri < 4; ++ri) {
        int row = r0 + tr * 4 + ri;
        if (row < N) {
            float4 o = make_float4(acc[ri][0] + bv2.x, acc[ri][1] + bv2.y,
                                   acc[ri][2] + bv2.z, acc[ri][3] + bv2.w);
            io4[(size_t)row * 32 + tc] = o;
        }
    }
}

extern "C" void kernel_launch(void* const* d_in, const int* in_sizes, int n_in,
                              void* d_out, int out_size, void* d_ws, size_t ws_size,
                              hipStream_t stream) {
    const float* x  = (const float*)d_in[0];
    const int*   ei = (const int*)d_in[1];
    const float* W1 = (const float*)d_in[2];
    const float* b1 = (const float*)d_in[3];
    const float* W2 = (const float*)d_in[4];
    const float* b2 = (const float*)d_in[5];
    float* out = (float*)d_out;

    // primary ws: xb[12.8MB] | sl[6.4MB] | cnt[200KB] | head[200KB] | nextsrc[5.12MB] | w1t | w2t
    const size_t xb_bytes   = (size_t)NNODES * DIM * 2;        // 12,800,000
    const size_t sl_bytes   = (size_t)NNODES * CAP * 2;        // 6,400,000
    const size_t cnt_bytes  = (size_t)NNODES * sizeof(int);    // 200,000
    const size_t head_bytes = (size_t)NNODES * sizeof(int);    // 200,000
    const size_t ns_bytes   = (size_t)NEDGES * sizeof(int2);   // 5,120,000
    const size_t wt_bytes   = (size_t)DIM * DIM * 2;           // 32,768
    const size_t need_full  = xb_bytes + sl_bytes + cnt_bytes + head_bytes + ns_bytes + 2 * wt_bytes;

    const size_t csr_ints = (size_t)(NNODES * 2 + (NNODES + 1) + NEDGES + 128);
    const size_t need_csr = csr_ints * sizeof(int);

    if (ws_size >= need_full) {
        char* p = (char*)d_ws;
        uint4* xb4  = (uint4*)p;                 p += xb_bytes;
        u16*   sl   = (u16*)p;                   p += sl_bytes;
        int*   cnt  = (int*)p;                   p += cnt_bytes;
        int*   head = (int*)p;                   p += head_bytes;
        int2*  nextsrc = (int2*)p;               p += ns_bytes;
        u16*   w1t  = (u16*)p;
        u16*   w2t  = w1t + DIM * DIM;

        prep_k<<<CVT_BLKS + CVTW_BLKS + INIT_BLKS, 256, 0, stream>>>(
            (const float4*)x, xb4, W1, W2, w1t, cnt, head);
        fillpad_k<<<(NEDGES + 255) / 256, 256, 0, stream>>>(ei, cnt, sl, head, nextsrc, NEDGES);
        gathermlp_k<<<(NNODES + 63) / 64, 256, 0, stream>>>(
            (const u16*)xb4, cnt, sl, head, nextsrc, out, w1t, b1, w2t, b2);
    } else if (ws_size >= need_csr) {
        int* deg = (int*)d_ws;
        int* cur = deg + NNODES;
        int* off = cur + NNODES;
        int* srclist = off + NNODES + 1;
        int* bsum = srclist + NEDGES;
        zero_k<<<(NNODES + 255) / 256, 256, 0, stream>>>(deg, NNODES);
        hist_k<<<(NEDGES + 255) / 256, 256, 0, stream>>>(ei, deg, NEDGES);
        scanA_k<<<SCAN_BLK, 256, 0, stream>>>(deg, bsum);
        scanC_k<<<SCAN_BLK, 256, 0, stream>>>(deg, bsum, off, cur);
        fill_k<<<(NEDGES + 255) / 256, 256, 0, stream>>>(ei, cur, srclist, NEDGES);
        gather_k<<<(NNODES * 32 + 255) / 256, 256, 0, stream>>>(
            (const float4*)x, off, srclist, (float4*)out);
        mlp_k<<<(NNODES + 31) / 32, 256, 0, stream>>>(out, W1, b1, W2, b2, NNODES);
    } else {
        int n4 = NNODES * DIM / 4;
        copy_k<<<(n4 + 255) / 256, 256, 0, stream>>>((const float4*)x, (float4*)out, n4);
        scatter_k<<<(NEDGES * 32 + 255) / 256, 256, 0, stream>>>((const float4*)x, ei, out, NEDGES);
        mlp_k<<<(NNODES + 31) / 32, 256, 0, stream>>>(out, W1, b1, W2, b2, NNODES);
    }
}